// Round 10
// baseline (154.944 us; speedup 1.0000x reference)
//
#include <hip/hip_runtime.h>

typedef unsigned short u16;
typedef unsigned int u32;
typedef __attribute__((ext_vector_type(8))) short bf16x8;
typedef __attribute__((ext_vector_type(4))) float f32x4;
typedef __attribute__((ext_vector_type(16))) float f32x16;
typedef __attribute__((ext_vector_type(4))) u32 u32x4;

#define MFMA16(a, b, c) __builtin_amdgcn_mfma_f32_16x16x32_bf16((a), (b), (c), 0, 0, 0)
#define MFMA32(a, b, c) __builtin_amdgcn_mfma_f32_32x32x16_bf16((a), (b), (c), 0, 0, 0)

__device__ __forceinline__ void async_lds16(void* lds, const void* g) {
  __builtin_amdgcn_global_load_lds(
      (const __attribute__((address_space(1))) void*)g,
      (__attribute__((address_space(3))) void*)lds, 16, 0, 0);
}

__device__ __forceinline__ u16 f2bf(float f) {
  union { float f; unsigned u; } v; v.f = f;
  unsigned r = v.u + 0x7fffu + ((v.u >> 16) & 1u);
  return (u16)(r >> 16);
}

__device__ __forceinline__ u32 cvt_pk_bf16(float lo, float hi) {
  u32 r;
  asm("v_cvt_pk_bf16_f32 %0, %1, %2" : "=v"(r) : "v"(lo), "v"(hi));
  return r;
}

__device__ __forceinline__ float exp2_fast(float x) {
  float r;
  asm("v_exp_f32 %0, %1" : "=v"(r) : "v"(x));
  return r;
}

// swaps a's hi-32 lanes with b's lo-32 lanes
__device__ __forceinline__ void pswap(u32& a, u32& b) {
  asm("v_permlane32_swap_b32 %0, %1" : "+v"(a), "+v"(b));
}

// ---------------- preprocess kernels ----------------

__global__ __launch_bounds__(256) void k_cvt(const float* __restrict__ in, u16* __restrict__ out, int n) {
  int i = (blockIdx.x * 256 + threadIdx.x) * 4;
  if (i >= n) return;
  float4 v = *(const float4*)(in + i);
  ushort4 o;
  o.x = f2bf(v.x); o.y = f2bf(v.y); o.z = f2bf(v.z); o.w = f2bf(v.w);
  *(ushort4*)(out + i) = o;
}

// in: f32 [R][C]  ->  out: bf16 [C][R]
__global__ __launch_bounds__(256) void k_transpose_cvt(const float* __restrict__ in, u16* __restrict__ out,
                                                       int R, int C) {
  __shared__ float tile[32][33];
  int c0 = blockIdx.x * 32, r0 = blockIdx.y * 32;
  int tx = threadIdx.x & 31, ty = threadIdx.x >> 5;
#pragma unroll
  for (int i = 0; i < 32; i += 8)
    tile[ty + i][tx] = in[(long)(r0 + ty + i) * C + c0 + tx];
  __syncthreads();
#pragma unroll
  for (int i = 0; i < 32; i += 8)
    out[(long)(c0 + ty + i) * R + r0 + tx] = f2bf(tile[tx][ty + i]);
}

// V [32 bh][2048 s][64 d] -> Vt [32 bh][64 d][2048 s]   (bf16)
__global__ __launch_bounds__(256) void k_transpose_v(const u16* __restrict__ V, u16* __restrict__ Vt) {
  int bh = blockIdx.z;
  int s0 = blockIdx.x * 32, d0 = blockIdx.y * 32;
  __shared__ u16 tile[32][33];
  int tx = threadIdx.x & 31, ty = threadIdx.x >> 5;
  const u16* Vb = V + (long)bh * 2048 * 64;
  u16* Vtb = Vt + (long)bh * 64 * 2048;
#pragma unroll
  for (int i = 0; i < 32; i += 8)
    tile[ty + i][tx] = Vb[(long)(s0 + ty + i) * 64 + d0 + tx];
  __syncthreads();
#pragma unroll
  for (int i = 0; i < 32; i += 8)
    Vtb[(long)(d0 + ty + i) * 2048 + s0 + tx] = tile[tx][ty + i];
}

// ---------------- NT GEMM core: C[128x128] = A[128xK] * Bt[128xK]^T ----------------

__device__ __forceinline__ void gemm_core(const u16* __restrict__ A, const u16* __restrict__ Bt,
                                          int K, long row0, long col0,
                                          u16* sA, u16* sB, f32x4 acc[4][4]) {
  const int t = threadIdx.x;
  const int lane = t & 63, g = lane >> 4, m16 = lane & 15;
  const int wid = t >> 6, wr = wid >> 1, wc = wid & 1;
  const int ldsbase = (t & ~63) << 4;
  const int nkt = K >> 6;
  for (int kt = 0; kt < nkt; ++kt) {
    const int k0 = kt << 6;
    __syncthreads();
#pragma unroll
    for (int it = 0; it < 4; ++it) {
      int i = it * 256 + t;
      int r = i >> 3, c = i & 7;
      int cs = c ^ (r & 7);
      async_lds16((char*)sA + it * 4096 + ldsbase, A + (row0 + r) * K + k0 + cs * 8);
    }
#pragma unroll
    for (int it = 0; it < 4; ++it) {
      int i = it * 256 + t;
      int r = i >> 3, c = i & 7;
      int cs = c ^ (r & 7);
      async_lds16((char*)sB + it * 4096 + ldsbase, Bt + (col0 + r) * K + k0 + cs * 8);
    }
    __syncthreads();
#pragma unroll
    for (int kk6 = 0; kk6 < 2; ++kk6) {
      const int ke = kk6 * 32 + 8 * g;
      bf16x8 av[4], bv[4];
#pragma unroll
      for (int mi = 0; mi < 4; ++mi) {
        int row = wr * 64 + mi * 16 + m16;
        av[mi] = *(const bf16x8*)((const char*)sA + (row << 7) + ((ke << 1) ^ ((row & 7) << 4)));
      }
#pragma unroll
      for (int ni = 0; ni < 4; ++ni) {
        int row = wc * 64 + ni * 16 + m16;
        bv[ni] = *(const bf16x8*)((const char*)sB + (row << 7) + ((ke << 1) ^ ((row & 7) << 4)));
      }
#pragma unroll
      for (int mi = 0; mi < 4; ++mi)
#pragma unroll
        for (int ni = 0; ni < 4; ++ni)
          acc[mi][ni] = MFMA16(av[mi], bv[ni], acc[mi][ni]);
    }
  }
}

// GEMM1: xb[4096][1024] x wqkvT[3072][1024]^T -> scatter Q,K,V [B,H,S,D] bf16
// Q scaled by 1/sqrt(64) * log2(e) so attention can use exp2 directly.
__global__ __launch_bounds__(256) void k_gemm_qkv(const u16* __restrict__ xb, const u16* __restrict__ wT,
                                                  u16* __restrict__ Qo, u16* __restrict__ Ko,
                                                  u16* __restrict__ Vo) {
  __shared__ __align__(16) u16 sA[128 * 64];
  __shared__ __align__(16) u16 sB[128 * 64];
  f32x4 acc[4][4];
  const f32x4 z = {0.f, 0.f, 0.f, 0.f};
#pragma unroll
  for (int mi = 0; mi < 4; ++mi)
#pragma unroll
    for (int ni = 0; ni < 4; ++ni) acc[mi][ni] = z;
  long row0 = (long)blockIdx.y * 128, col0 = (long)blockIdx.x * 128;
  gemm_core(xb, wT, 1024, row0, col0, sA, sB, acc);
  const int t = threadIdx.x;
  const int lane = t & 63, g = lane >> 4, m16 = lane & 15;
  const int wid = t >> 6, wr = wid >> 1, wc = wid & 1;
#pragma unroll
  for (int mi = 0; mi < 4; ++mi) {
#pragma unroll
    for (int ni = 0; ni < 4; ++ni) {
#pragma unroll
      for (int r = 0; r < 4; ++r) {
        int row = (int)row0 + wr * 64 + mi * 16 + 4 * g + r;
        int col = (int)col0 + wc * 64 + ni * 16 + m16;
        int h = col / 192, rem = col - h * 192;
        int which = rem >> 6, d = rem & 63;
        int b = row >> 11, s = row & 2047;
        long off = (((long)(b * 16 + h)) * 2048 + s) * 64 + d;
        float v = acc[mi][ni][r];
        if (which == 0) Qo[off] = f2bf(v * 0.18033688f);  // 0.125 * log2(e)
        else if (which == 1) Ko[off] = f2bf(v);
        else Vo[off] = f2bf(v);
      }
    }
  }
}

// GEMM2: Ob[4096][1024] x woutT[1024][1024]^T -> out f32 [4096][1024]
__global__ __launch_bounds__(256) void k_gemm_out(const u16* __restrict__ Ob, const u16* __restrict__ wT,
                                                  float* __restrict__ out) {
  __shared__ __align__(16) u16 sA[128 * 64];
  __shared__ __align__(16) u16 sB[128 * 64];
  f32x4 acc[4][4];
  const f32x4 z = {0.f, 0.f, 0.f, 0.f};
#pragma unroll
  for (int mi = 0; mi < 4; ++mi)
#pragma unroll
    for (int ni = 0; ni < 4; ++ni) acc[mi][ni] = z;
  long row0 = (long)blockIdx.y * 128, col0 = (long)blockIdx.x * 128;
  gemm_core(Ob, wT, 1024, row0, col0, sA, sB, acc);
  const int t = threadIdx.x;
  const int lane = t & 63, g = lane >> 4, m16 = lane & 15;
  const int wid = t >> 6, wr = wid >> 1, wc = wid & 1;
#pragma unroll
  for (int mi = 0; mi < 4; ++mi) {
#pragma unroll
    for (int ni = 0; ni < 4; ++ni) {
#pragma unroll
      for (int r = 0; r < 4; ++r) {
        long row = row0 + wr * 64 + mi * 16 + 4 * g + r;
        long col = col0 + wc * 64 + ni * 16 + m16;
        out[row * 1024 + col] = acc[mi][ni][r];
      }
    }
  }
}

// ---------------- causal flash attention: in-register, 2-wave block split-K ----------------
// Block (bh, p) = 128 thr = 2 waves; wave w handles k-blocks === w (mod 2) of strips
// p and 63-p (33/32 blocks per wave, uniform). Fixed-max softmax => partials linear;
// combined through 8.4KB LDS at strip end. Main loop barrier-free, 1-deep pipelined.

struct KVfrag {
  bf16x8 k0, k1, k2, k3, v00, v01, v10, v11;
};

__device__ __forceinline__ void load_kv(KVfrag& f, const u16* Kb, const u16* Vb, int ko) {
  const u16* kp = Kb + ko * 64;
  f.k0 = *(const bf16x8*)(kp);
  f.k1 = *(const bf16x8*)(kp + 16);
  f.k2 = *(const bf16x8*)(kp + 32);
  f.k3 = *(const bf16x8*)(kp + 48);
  const u16* vp = Vb + ko;
  f.v00 = *(const bf16x8*)(vp);
  f.v01 = *(const bf16x8*)(vp + 65536);
  f.v10 = *(const bf16x8*)(vp + 16);
  f.v11 = *(const bf16x8*)(vp + 65536 + 16);
}

template <bool DIAG>
__device__ __forceinline__ void attn_block32(const KVfrag& f,
                                             bf16x8 qf0, bf16x8 qf1, bf16x8 qf2, bf16x8 qf3,
                                             f32x16& acc0, f32x16& acc1, float& l,
                                             int q5, int hi) {
  f32x16 s;
#pragma unroll
  for (int r = 0; r < 16; ++r) s[r] = 0.f;
  s = MFMA32(f.k0, qf0, s);
  s = MFMA32(f.k1, qf1, s);
  s = MFMA32(f.k2, qf2, s);
  s = MFMA32(f.k3, qf3, s);

  float p[16];
#pragma unroll
  for (int r = 0; r < 16; ++r) {
    float pv = exp2_fast(s[r]);
    if (DIAG) {
      int crow = (r & 3) + 8 * (r >> 2) + 4 * hi;
      pv = (crow <= q5) ? pv : 0.f;
    }
    p[r] = pv;
  }
  l += (((p[0] + p[1]) + (p[2] + p[3])) + ((p[4] + p[5]) + (p[6] + p[7]))) +
       (((p[8] + p[9]) + (p[10] + p[11])) + ((p[12] + p[13]) + (p[14] + p[15])));

  u32 a0 = cvt_pk_bf16(p[0], p[1]), a1 = cvt_pk_bf16(p[2], p[3]);
  u32 b0 = cvt_pk_bf16(p[4], p[5]), b1 = cvt_pk_bf16(p[6], p[7]);
  pswap(a0, b0); pswap(a1, b1);
  u32 c0 = cvt_pk_bf16(p[8], p[9]), c1 = cvt_pk_bf16(p[10], p[11]);
  u32 d0 = cvt_pk_bf16(p[12], p[13]), d1 = cvt_pk_bf16(p[14], p[15]);
  pswap(c0, d0); pswap(c1, d1);
  u32x4 t0; t0[0] = a0; t0[1] = a1; t0[2] = b0; t0[3] = b1;
  u32x4 t1; t1[0] = c0; t1[1] = c1; t1[2] = d0; t1[3] = d1;
  bf16x8 pa0 = __builtin_bit_cast(bf16x8, t0);  // keys ko+0..15, k-slot order
  bf16x8 pa1 = __builtin_bit_cast(bf16x8, t1);  // keys ko+16..31

  acc0 = MFMA32(pa0, f.v00, acc0);
  acc1 = MFMA32(pa0, f.v01, acc1);
  acc0 = MFMA32(pa1, f.v10, acc0);
  acc1 = MFMA32(pa1, f.v11, acc1);
}

// Q,K: [32 bh][2048][64] bf16 (Q pre-scaled by 0.125*log2e); Vt: [32 bh][64][2048] bf16
__global__ __launch_bounds__(128) void k_attn(const u16* __restrict__ Qg, const u16* __restrict__ Kg,
                                              const u16* __restrict__ Vtg, u16* __restrict__ Og) {
  __shared__ float sX[2 * 32 * 32];  // [wave][crow][q5] partner-half exchange (8KB)
  __shared__ float sL[2][32];
  const int t = threadIdx.x;
  const int lane = t & 63, q5 = lane & 31, hi = lane >> 5, w = t >> 6;
  const int L = blockIdx.x;
  const int bh = L & 31, p = L >> 5;  // XCD affinity: L%8 == bh%8; p in [0,32)
  const int b = bh >> 4, h = bh & 15;
  const u16* Qh = Qg + (long)bh * 131072;
  const u16* Kh = Kg + (long)bh * 131072;
  const u16* Vh = Vtg + (long)bh * 131072;
  const long orow_base = (long)b * 2048;
  const u16* Kb = Kh + q5 * 64 + hi * 8;
  const u16* Vb = Vh + q5 * 2048 + hi * 8;

#pragma unroll 1
  for (int half = 0; half < 2; ++half) {
    const int strip = half ? (63 - p) : p;
    const int q0w = strip * 32;
    const u16* Qp = Qh + (q0w + q5) * 64 + hi * 8;
    bf16x8 qf0 = *(const bf16x8*)(Qp);
    bf16x8 qf1 = *(const bf16x8*)(Qp + 16);
    bf16x8 qf2 = *(const bf16x8*)(Qp + 32);
    bf16x8 qf3 = *(const bf16x8*)(Qp + 48);

    f32x16 acc0, acc1;
#pragma unroll
    for (int r = 0; r < 16; ++r) { acc0[r] = 0.f; acc1[r] = 0.f; }
    float l = 0.f;

    // wave w's blocks: b32 = w, w+2, ... <= strip; diag iff (strip-w) even
    const int cnt = (strip >= w) ? (((strip - w) >> 1) + 1) : 0;
    const bool dm = (strip >= w) && (((strip - w) & 1) == 0);
    const int nnd = dm ? cnt - 1 : cnt;

    if (cnt > 0) {
      KVfrag fA, fB;
      load_kv(fA, Kb, Vb, w * 32);
      if (nnd == 0) {
        attn_block32<true>(fA, qf0, qf1, qf2, qf3, acc0, acc1, l, q5, hi);
      } else {
        int i = 0;
        while (true) {
          {
            int nx = (i + 1 < cnt) ? (w + 2 * (i + 1)) : (w + 2 * i);
            load_kv(fB, Kb, Vb, nx * 32);
            attn_block32<false>(fA, qf0, qf1, qf2, qf3, acc0, acc1, l, q5, hi);
            ++i;
            if (i == nnd) { if (dm) attn_block32<true>(fB, qf0, qf1, qf2, qf3, acc0, acc1, l, q5, hi); break; }
          }
          {
            int nx = (i + 1 < cnt) ? (w + 2 * (i + 1)) : (w + 2 * i);
            load_kv(fA, Kb, Vb, nx * 32);
            attn_block32<false>(fB, qf0, qf1, qf2, qf3, acc0, acc1, l, q5, hi);
            ++i;
            if (i == nnd) { if (dm) attn_block32<true>(fA, qf0, qf1, qf2, qf3, acc0, acc1, l, q5, hi); break; }
          }
        }
      }
    }

    l += __shfl_xor(l, 32);

    // ---- in-block split-K combine (wave w outputs d-half w, shares the other)
    __syncthreads();  // protect previous strip's LDS reads
    float* sXw = sX + w * 1024;
#pragma unroll
    for (int r = 0; r < 16; ++r) {
      int crow = (r & 3) + 8 * (r >> 2) + 4 * hi;
      sXw[crow * 32 + q5] = (w == 0) ? acc1[r] : acc0[r];
    }
    if (hi == 0) sL[w][q5] = l;
    __syncthreads();
    float ltot = sL[0][q5] + sL[1][q5];
    float linv = 1.0f / ltot;
    const float* sXp = sX + (1 - w) * 1024;
#pragma unroll
    for (int r = 0; r < 16; ++r) {
      int crow = (r & 3) + 8 * (r >> 2) + 4 * hi;
      float own = (w == 0) ? acc0[r] : acc1[r];
      float tot = own + sXp[crow * 32 + q5];
      float lf = __shfl(linv, crow);
      long orow = orow_base + q0w + crow;
      Og[orow * 1024 + h * 64 + w * 32 + q5] = f2bf(tot * lf);
    }
  }
}

// ---------------- launch ----------------

extern "C" void kernel_launch(void* const* d_in, const int* in_sizes, int n_in,
                              void* d_out, int out_size, void* d_ws, size_t ws_size,
                              hipStream_t stream) {
  const float* x = (const float*)d_in[0];
  const float* w_qkv = (const float*)d_in[1];
  const float* w_out = (const float*)d_in[2];
  float* out = (float*)d_out;
  char* ws = (char*)d_ws;

  u16* xb    = (u16*)(ws + 0);          // 8 MB, reused as Ob after attention
  u16* wqkvT = (u16*)(ws + 8388608L);   // 6 MB
  u16* woutT = (u16*)(ws + 14680064L);  // 2 MB
  u16* Qb    = (u16*)(ws + 16777216L);  // 8 MB
  u16* Kb    = (u16*)(ws + 25165824L);  // 8 MB
  u16* Vb    = (u16*)(ws + 33554432L);  // 8 MB
  u16* Vt    = (u16*)(ws + 41943040L);  // 8 MB  (total 48 MB)
  u16* Ob    = xb;                      // alias: xb dead after GEMM1

  k_cvt<<<4096, 256, 0, stream>>>(x, xb, 4194304);
  k_transpose_cvt<<<dim3(96, 32), 256, 0, stream>>>(w_qkv, wqkvT, 1024, 3072);
  k_transpose_cvt<<<dim3(32, 32), 256, 0, stream>>>(w_out, woutT, 1024, 1024);
  k_gemm_qkv<<<dim3(24, 32), 256, 0, stream>>>(xb, wqkvT, Qb, Kb, Vb);
  k_transpose_v<<<dim3(64, 2, 32), 256, 0, stream>>>(Vb, Vt);
  k_attn<<<dim3(1024), 128, 0, stream>>>(Qb, Kb, Vt, Ob);
  k_gemm_out<<<dim3(8, 32), 256, 0, stream>>>(Ob, woutT, out);
}

// Round 11
// 133.517 us; speedup vs baseline: 1.1605x; 1.1605x over previous
//
#include <hip/hip_runtime.h>

typedef unsigned short u16;
typedef unsigned int u32;
typedef __attribute__((ext_vector_type(8))) short bf16x8;
typedef __attribute__((ext_vector_type(4))) float f32x4;
typedef __attribute__((ext_vector_type(16))) float f32x16;
typedef __attribute__((ext_vector_type(4))) u32 u32x4;

#define MFMA16(a, b, c) __builtin_amdgcn_mfma_f32_16x16x32_bf16((a), (b), (c), 0, 0, 0)
#define MFMA32(a, b, c) __builtin_amdgcn_mfma_f32_32x32x16_bf16((a), (b), (c), 0, 0, 0)

__device__ __forceinline__ void async_lds16(void* lds, const void* g) {
  __builtin_amdgcn_global_load_lds(
      (const __attribute__((address_space(1))) void*)g,
      (__attribute__((address_space(3))) void*)lds, 16, 0, 0);
}

__device__ __forceinline__ u16 f2bf(float f) {
  union { float f; unsigned u; } v; v.f = f;
  unsigned r = v.u + 0x7fffu + ((v.u >> 16) & 1u);
  return (u16)(r >> 16);
}

__device__ __forceinline__ u32 cvt_pk_bf16(float lo, float hi) {
  u32 r;
  asm("v_cvt_pk_bf16_f32 %0, %1, %2" : "=v"(r) : "v"(lo), "v"(hi));
  return r;
}

__device__ __forceinline__ float exp2_fast(float x) {
  float r;
  asm("v_exp_f32 %0, %1" : "=v"(r) : "v"(x));
  return r;
}

// swaps a's hi-32 lanes with b's lo-32 lanes
__device__ __forceinline__ void pswap(u32& a, u32& b) {
  asm("v_permlane32_swap_b32 %0, %1" : "+v"(a), "+v"(b));
}

// ---------------- preprocess kernels ----------------

__global__ __launch_bounds__(256) void k_cvt(const float* __restrict__ in, u16* __restrict__ out, int n) {
  int i = (blockIdx.x * 256 + threadIdx.x) * 4;
  if (i >= n) return;
  float4 v = *(const float4*)(in + i);
  ushort4 o;
  o.x = f2bf(v.x); o.y = f2bf(v.y); o.z = f2bf(v.z); o.w = f2bf(v.w);
  *(ushort4*)(out + i) = o;
}

// in: f32 [R][C]  ->  out: bf16 [C][R]
__global__ __launch_bounds__(256) void k_transpose_cvt(const float* __restrict__ in, u16* __restrict__ out,
                                                       int R, int C) {
  __shared__ float tile[32][33];
  int c0 = blockIdx.x * 32, r0 = blockIdx.y * 32;
  int tx = threadIdx.x & 31, ty = threadIdx.x >> 5;
#pragma unroll
  for (int i = 0; i < 32; i += 8)
    tile[ty + i][tx] = in[(long)(r0 + ty + i) * C + c0 + tx];
  __syncthreads();
#pragma unroll
  for (int i = 0; i < 32; i += 8)
    out[(long)(c0 + ty + i) * R + r0 + tx] = f2bf(tile[tx][ty + i]);
}

// V [32 bh][2048 s][64 d] -> Vt [32 bh][64 d][2048 s]   (bf16)
__global__ __launch_bounds__(256) void k_transpose_v(const u16* __restrict__ V, u16* __restrict__ Vt) {
  int bh = blockIdx.z;
  int s0 = blockIdx.x * 32, d0 = blockIdx.y * 32;
  __shared__ u16 tile[32][33];
  int tx = threadIdx.x & 31, ty = threadIdx.x >> 5;
  const u16* Vb = V + (long)bh * 2048 * 64;
  u16* Vtb = Vt + (long)bh * 64 * 2048;
#pragma unroll
  for (int i = 0; i < 32; i += 8)
    tile[ty + i][tx] = Vb[(long)(s0 + ty + i) * 64 + d0 + tx];
  __syncthreads();
#pragma unroll
  for (int i = 0; i < 32; i += 8)
    Vtb[(long)(d0 + ty + i) * 2048 + s0 + tx] = tile[tx][ty + i];
}

// ---------------- NT GEMM core: C[128x128] = A[128xK] * Bt[128xK]^T ----------------

__device__ __forceinline__ void gemm_core(const u16* __restrict__ A, const u16* __restrict__ Bt,
                                          int K, long row0, long col0,
                                          u16* sA, u16* sB, f32x4 acc[4][4]) {
  const int t = threadIdx.x;
  const int lane = t & 63, g = lane >> 4, m16 = lane & 15;
  const int wid = t >> 6, wr = wid >> 1, wc = wid & 1;
  const int ldsbase = (t & ~63) << 4;
  const int nkt = K >> 6;
  for (int kt = 0; kt < nkt; ++kt) {
    const int k0 = kt << 6;
    __syncthreads();
#pragma unroll
    for (int it = 0; it < 4; ++it) {
      int i = it * 256 + t;
      int r = i >> 3, c = i & 7;
      int cs = c ^ (r & 7);
      async_lds16((char*)sA + it * 4096 + ldsbase, A + (row0 + r) * K + k0 + cs * 8);
    }
#pragma unroll
    for (int it = 0; it < 4; ++it) {
      int i = it * 256 + t;
      int r = i >> 3, c = i & 7;
      int cs = c ^ (r & 7);
      async_lds16((char*)sB + it * 4096 + ldsbase, Bt + (col0 + r) * K + k0 + cs * 8);
    }
    __syncthreads();
#pragma unroll
    for (int kk6 = 0; kk6 < 2; ++kk6) {
      const int ke = kk6 * 32 + 8 * g;
      bf16x8 av[4], bv[4];
#pragma unroll
      for (int mi = 0; mi < 4; ++mi) {
        int row = wr * 64 + mi * 16 + m16;
        av[mi] = *(const bf16x8*)((const char*)sA + (row << 7) + ((ke << 1) ^ ((row & 7) << 4)));
      }
#pragma unroll
      for (int ni = 0; ni < 4; ++ni) {
        int row = wc * 64 + ni * 16 + m16;
        bv[ni] = *(const bf16x8*)((const char*)sB + (row << 7) + ((ke << 1) ^ ((row & 7) << 4)));
      }
#pragma unroll
      for (int mi = 0; mi < 4; ++mi)
#pragma unroll
        for (int ni = 0; ni < 4; ++ni)
          acc[mi][ni] = MFMA16(av[mi], bv[ni], acc[mi][ni]);
    }
  }
}

// GEMM1: xb[4096][1024] x wqkvT[3072][1024]^T -> scatter Q,K,V [B,H,S,D] bf16
// Q scaled by 1/sqrt(64) * log2(e) so attention can use exp2 directly.
__global__ __launch_bounds__(256) void k_gemm_qkv(const u16* __restrict__ xb, const u16* __restrict__ wT,
                                                  u16* __restrict__ Qo, u16* __restrict__ Ko,
                                                  u16* __restrict__ Vo) {
  __shared__ __align__(16) u16 sA[128 * 64];
  __shared__ __align__(16) u16 sB[128 * 64];
  f32x4 acc[4][4];
  const f32x4 z = {0.f, 0.f, 0.f, 0.f};
#pragma unroll
  for (int mi = 0; mi < 4; ++mi)
#pragma unroll
    for (int ni = 0; ni < 4; ++ni) acc[mi][ni] = z;
  long row0 = (long)blockIdx.y * 128, col0 = (long)blockIdx.x * 128;
  gemm_core(xb, wT, 1024, row0, col0, sA, sB, acc);
  const int t = threadIdx.x;
  const int lane = t & 63, g = lane >> 4, m16 = lane & 15;
  const int wid = t >> 6, wr = wid >> 1, wc = wid & 1;
#pragma unroll
  for (int mi = 0; mi < 4; ++mi) {
#pragma unroll
    for (int ni = 0; ni < 4; ++ni) {
#pragma unroll
      for (int r = 0; r < 4; ++r) {
        int row = (int)row0 + wr * 64 + mi * 16 + 4 * g + r;
        int col = (int)col0 + wc * 64 + ni * 16 + m16;
        int h = col / 192, rem = col - h * 192;
        int which = rem >> 6, d = rem & 63;
        int b = row >> 11, s = row & 2047;
        long off = (((long)(b * 16 + h)) * 2048 + s) * 64 + d;
        float v = acc[mi][ni][r];
        if (which == 0) Qo[off] = f2bf(v * 0.18033688f);  // 0.125 * log2(e)
        else if (which == 1) Ko[off] = f2bf(v);
        else Vo[off] = f2bf(v);
      }
    }
  }
}

// GEMM2: Ob[4096][1024] x woutT[1024][1024]^T -> out f32 [4096][1024]
__global__ __launch_bounds__(256) void k_gemm_out(const u16* __restrict__ Ob, const u16* __restrict__ wT,
                                                  float* __restrict__ out) {
  __shared__ __align__(16) u16 sA[128 * 64];
  __shared__ __align__(16) u16 sB[128 * 64];
  f32x4 acc[4][4];
  const f32x4 z = {0.f, 0.f, 0.f, 0.f};
#pragma unroll
  for (int mi = 0; mi < 4; ++mi)
#pragma unroll
    for (int ni = 0; ni < 4; ++ni) acc[mi][ni] = z;
  long row0 = (long)blockIdx.y * 128, col0 = (long)blockIdx.x * 128;
  gemm_core(Ob, wT, 1024, row0, col0, sA, sB, acc);
  const int t = threadIdx.x;
  const int lane = t & 63, g = lane >> 4, m16 = lane & 15;
  const int wid = t >> 6, wr = wid >> 1, wc = wid & 1;
#pragma unroll
  for (int mi = 0; mi < 4; ++mi) {
#pragma unroll
    for (int ni = 0; ni < 4; ++ni) {
#pragma unroll
      for (int r = 0; r < 4; ++r) {
        long row = row0 + wr * 64 + mi * 16 + 4 * g + r;
        long col = col0 + wc * 64 + ni * 16 + m16;
        out[row * 1024 + col] = acc[mi][ni][r];
      }
    }
  }
}

// ---------------- causal flash attention: LDS-shared K/V + lean in-register body ----------------
// Block = 256 thr = 4 waves, QBLK=128 (wave w -> strip qt*4+w), KVBLK=64, K/V
// double-buffered in LDS (32KB) via global_load_lds shared by all 4 waves -> 4x less
// global K/V traffic. Per-wave math identical to the verified in-register version:
// swapped QK 32x32 (lane owns q-col), fixed-max exp2 softmax, permlane P->PV. One
// barrier per tile (dbuf); wave-dead sub-blocks skipped.

template <bool DIAG>
__device__ __forceinline__ void attn_sub(const char* Kt, const char* Vt, int bsub,
                                         bf16x8 qf0, bf16x8 qf1, bf16x8 qf2, bf16x8 qf3,
                                         f32x16& acc0, f32x16& acc1, float& l,
                                         int q5, int hi) {
  const int x7 = q5 & 7;
  const int rowK = (bsub * 32 + q5) << 7;
  bf16x8 k0 = *(const bf16x8*)(Kt + rowK + (((0 + hi) ^ x7) << 4));
  bf16x8 k1 = *(const bf16x8*)(Kt + rowK + (((2 + hi) ^ x7) << 4));
  bf16x8 k2 = *(const bf16x8*)(Kt + rowK + (((4 + hi) ^ x7) << 4));
  bf16x8 k3 = *(const bf16x8*)(Kt + rowK + (((6 + hi) ^ x7) << 4));
  const int rowV0 = q5 << 7, rowV1 = (q5 + 32) << 7;
  bf16x8 v00 = *(const bf16x8*)(Vt + rowV0 + (((bsub * 4 + 0 + hi) ^ x7) << 4));
  bf16x8 v01 = *(const bf16x8*)(Vt + rowV1 + (((bsub * 4 + 0 + hi) ^ x7) << 4));
  bf16x8 v10 = *(const bf16x8*)(Vt + rowV0 + (((bsub * 4 + 2 + hi) ^ x7) << 4));
  bf16x8 v11 = *(const bf16x8*)(Vt + rowV1 + (((bsub * 4 + 2 + hi) ^ x7) << 4));

  f32x16 s;
#pragma unroll
  for (int r = 0; r < 16; ++r) s[r] = 0.f;
  s = MFMA32(k0, qf0, s);
  s = MFMA32(k1, qf1, s);
  s = MFMA32(k2, qf2, s);
  s = MFMA32(k3, qf3, s);

  float p[16];
#pragma unroll
  for (int r = 0; r < 16; ++r) {
    float pv = exp2_fast(s[r]);
    if (DIAG) {
      int crow = (r & 3) + 8 * (r >> 2) + 4 * hi;
      pv = (crow <= q5) ? pv : 0.f;
    }
    p[r] = pv;
  }
  l += (((p[0] + p[1]) + (p[2] + p[3])) + ((p[4] + p[5]) + (p[6] + p[7]))) +
       (((p[8] + p[9]) + (p[10] + p[11])) + ((p[12] + p[13]) + (p[14] + p[15])));

  u32 a0 = cvt_pk_bf16(p[0], p[1]), a1 = cvt_pk_bf16(p[2], p[3]);
  u32 b0 = cvt_pk_bf16(p[4], p[5]), b1 = cvt_pk_bf16(p[6], p[7]);
  pswap(a0, b0); pswap(a1, b1);
  u32 c0 = cvt_pk_bf16(p[8], p[9]), c1 = cvt_pk_bf16(p[10], p[11]);
  u32 d0 = cvt_pk_bf16(p[12], p[13]), d1 = cvt_pk_bf16(p[14], p[15]);
  pswap(c0, d0); pswap(c1, d1);
  u32x4 t0; t0[0] = a0; t0[1] = a1; t0[2] = b0; t0[3] = b1;
  u32x4 t1; t1[0] = c0; t1[1] = c1; t1[2] = d0; t1[3] = d1;
  bf16x8 pa0 = __builtin_bit_cast(bf16x8, t0);  // keys +0..15, k-slot order
  bf16x8 pa1 = __builtin_bit_cast(bf16x8, t1);  // keys +16..31

  acc0 = MFMA32(pa0, v00, acc0);
  acc1 = MFMA32(pa0, v01, acc1);
  acc0 = MFMA32(pa1, v10, acc0);
  acc1 = MFMA32(pa1, v11, acc1);
}

// Q,K: [32 bh][2048][64] bf16 (Q pre-scaled by 0.125*log2e); Vt: [32 bh][64][2048] bf16
__global__ __launch_bounds__(256) void k_attn(const u16* __restrict__ Qg, const u16* __restrict__ Kg,
                                              const u16* __restrict__ Vtg, u16* __restrict__ Og) {
  __shared__ __align__(16) u16 sK[2][64 * 64];  // [key][d] swizzled, 8KB per buffer
  __shared__ __align__(16) u16 sV[2][64 * 64];  // [d][key] swizzled
  const int t = threadIdx.x;
  const int lane = t & 63, q5 = lane & 31, hi = lane >> 5, w = t >> 6;
  const int L = blockIdx.x;
  const int bh = L & 31, q16 = L >> 5;                 // XCD affinity: L%8 == bh%8
  const int qt = (q16 < 8) ? q16 : (23 - q16);         // (qt, 15-qt) complementary ordering
  const int b = bh >> 4, h = bh & 15;
  const u16* Qh = Qg + (long)bh * 131072;
  const u16* Kh = Kg + (long)bh * 131072;
  const u16* Vh = Vtg + (long)bh * 131072;
  char* sKb = (char*)sK;
  char* sVb = (char*)sV;

  const int strip = qt * 4 + w;
  const int q0w = strip * 32;
  const int nkt = 2 * qt + 2;  // tiles staged by this block

  // Q fragments for this wave's strip
  const u16* Qp = Qh + (long)(q0w + q5) * 64 + hi * 8;
  bf16x8 qf0 = *(const bf16x8*)(Qp);
  bf16x8 qf1 = *(const bf16x8*)(Qp + 16);
  bf16x8 qf2 = *(const bf16x8*)(Qp + 32);
  bf16x8 qf3 = *(const bf16x8*)(Qp + 48);

  f32x16 acc0, acc1;
#pragma unroll
  for (int r = 0; r < 16; ++r) { acc0[r] = 0.f; acc1[r] = 0.f; }
  float l = 0.f;

  auto stage = [&](int buf, int kt) {
    const int kbase = kt << 6;
#pragma unroll
    for (int ps = 0; ps < 2; ++ps) {
      int i = ps * 256 + t;
      int r = i >> 3, c = i & 7, cs = c ^ (r & 7);
      async_lds16(sKb + buf * 8192 + i * 16, Kh + (long)(kbase + r) * 64 + cs * 8);
    }
#pragma unroll
    for (int ps = 0; ps < 2; ++ps) {
      int i = ps * 256 + t;
      int d = i >> 3, c = i & 7, cs = c ^ (d & 7);
      async_lds16(sVb + buf * 8192 + i * 16, Vh + (long)d * 2048 + kbase + cs * 8);
    }
  };

  stage(0, 0);
  int cur = 0;
  for (int kt = 0; kt < nkt; ++kt) {
    __syncthreads();  // tile kt staged (vmcnt drain) + everyone done reading buf cur^1
    if (kt + 1 < nkt) stage(cur ^ 1, kt + 1);
    const char* Kt = sKb + cur * 8192;
    const char* Vt = sVb + cur * 8192;
    const int c2 = 2 * kt;
    if (c2 <= strip) {
      if (c2 == strip) attn_sub<true>(Kt, Vt, 0, qf0, qf1, qf2, qf3, acc0, acc1, l, q5, hi);
      else             attn_sub<false>(Kt, Vt, 0, qf0, qf1, qf2, qf3, acc0, acc1, l, q5, hi);
    }
    if (c2 + 1 <= strip) {
      if (c2 + 1 == strip) attn_sub<true>(Kt, Vt, 1, qf0, qf1, qf2, qf3, acc0, acc1, l, q5, hi);
      else                 attn_sub<false>(Kt, Vt, 1, qf0, qf1, qf2, qf3, acc0, acc1, l, q5, hi);
    }
    cur ^= 1;
  }

  // epilogue (no LDS use -> no final barrier)
  l += __shfl_xor(l, 32);
  float linv = 1.0f / l;
  const long orow_base = (long)b * 2048;
#pragma unroll
  for (int r = 0; r < 16; ++r) {
    int crow = (r & 3) + 8 * (r >> 2) + 4 * hi;
    float lf = __shfl(linv, crow);
    long orow = orow_base + q0w + crow;
    Og[orow * 1024 + h * 64 + q5] = f2bf(acc0[r] * lf);
    Og[orow * 1024 + h * 64 + 32 + q5] = f2bf(acc1[r] * lf);
  }
}

// ---------------- launch ----------------

extern "C" void kernel_launch(void* const* d_in, const int* in_sizes, int n_in,
                              void* d_out, int out_size, void* d_ws, size_t ws_size,
                              hipStream_t stream) {
  const float* x = (const float*)d_in[0];
  const float* w_qkv = (const float*)d_in[1];
  const float* w_out = (const float*)d_in[2];
  float* out = (float*)d_out;
  char* ws = (char*)d_ws;

  u16* xb    = (u16*)(ws + 0);          // 8 MB, reused as Ob after attention
  u16* wqkvT = (u16*)(ws + 8388608L);   // 6 MB
  u16* woutT = (u16*)(ws + 14680064L);  // 2 MB
  u16* Qb    = (u16*)(ws + 16777216L);  // 8 MB
  u16* Kb    = (u16*)(ws + 25165824L);  // 8 MB
  u16* Vb    = (u16*)(ws + 33554432L);  // 8 MB
  u16* Vt    = (u16*)(ws + 41943040L);  // 8 MB  (total 48 MB)
  u16* Ob    = xb;                      // alias: xb dead after GEMM1

  k_cvt<<<4096, 256, 0, stream>>>(x, xb, 4194304);
  k_transpose_cvt<<<dim3(96, 32), 256, 0, stream>>>(w_qkv, wqkvT, 1024, 3072);
  k_transpose_cvt<<<dim3(32, 32), 256, 0, stream>>>(w_out, woutT, 1024, 1024);
  k_gemm_qkv<<<dim3(24, 32), 256, 0, stream>>>(xb, wqkvT, Qb, Kb, Vb);
  k_transpose_v<<<dim3(64, 2, 32), 256, 0, stream>>>(Vb, Vt);
  k_attn<<<dim3(512), 256, 0, stream>>>(Qb, Kb, Vt, Ob);
  k_gemm_out<<<dim3(8, 32), 256, 0, stream>>>(Ob, woutT, out);
}

// Round 12
// 130.730 us; speedup vs baseline: 1.1852x; 1.0213x over previous
//
#include <hip/hip_runtime.h>

typedef unsigned short u16;
typedef unsigned int u32;
typedef __attribute__((ext_vector_type(8))) short bf16x8;
typedef __attribute__((ext_vector_type(4))) float f32x4;
typedef __attribute__((ext_vector_type(16))) float f32x16;
typedef __attribute__((ext_vector_type(4))) u32 u32x4;

#define MFMA16(a, b, c) __builtin_amdgcn_mfma_f32_16x16x32_bf16((a), (b), (c), 0, 0, 0)
#define MFMA32(a, b, c) __builtin_amdgcn_mfma_f32_32x32x16_bf16((a), (b), (c), 0, 0, 0)

__device__ __forceinline__ void async_lds16(void* lds, const void* g) {
  __builtin_amdgcn_global_load_lds(
      (const __attribute__((address_space(1))) void*)g,
      (__attribute__((address_space(3))) void*)lds, 16, 0, 0);
}

__device__ __forceinline__ u16 f2bf(float f) {
  union { float f; unsigned u; } v; v.f = f;
  unsigned r = v.u + 0x7fffu + ((v.u >> 16) & 1u);
  return (u16)(r >> 16);
}

__device__ __forceinline__ u32 cvt_pk_bf16(float lo, float hi) {
  u32 r;
  asm("v_cvt_pk_bf16_f32 %0, %1, %2" : "=v"(r) : "v"(lo), "v"(hi));
  return r;
}

__device__ __forceinline__ float exp2_fast(float x) {
  float r;
  asm("v_exp_f32 %0, %1" : "=v"(r) : "v"(x));
  return r;
}

// swaps a's hi-32 lanes with b's lo-32 lanes
__device__ __forceinline__ void pswap(u32& a, u32& b) {
  asm("v_permlane32_swap_b32 %0, %1" : "+v"(a), "+v"(b));
}

// ---------------- preprocess kernels ----------------

__global__ __launch_bounds__(256) void k_cvt(const float* __restrict__ in, u16* __restrict__ out, int n) {
  int i = (blockIdx.x * 256 + threadIdx.x) * 4;
  if (i >= n) return;
  float4 v = *(const float4*)(in + i);
  ushort4 o;
  o.x = f2bf(v.x); o.y = f2bf(v.y); o.z = f2bf(v.z); o.w = f2bf(v.w);
  *(ushort4*)(out + i) = o;
}

// in: f32 [R][C]  ->  out: bf16 [C][R]
__global__ __launch_bounds__(256) void k_transpose_cvt(const float* __restrict__ in, u16* __restrict__ out,
                                                       int R, int C) {
  __shared__ float tile[32][33];
  int c0 = blockIdx.x * 32, r0 = blockIdx.y * 32;
  int tx = threadIdx.x & 31, ty = threadIdx.x >> 5;
#pragma unroll
  for (int i = 0; i < 32; i += 8)
    tile[ty + i][tx] = in[(long)(r0 + ty + i) * C + c0 + tx];
  __syncthreads();
#pragma unroll
  for (int i = 0; i < 32; i += 8)
    out[(long)(c0 + ty + i) * R + r0 + tx] = f2bf(tile[tx][ty + i]);
}

// V [32 bh][2048 s][64 d] -> Vt [32 bh][64 d][2048 s]   (bf16)
__global__ __launch_bounds__(256) void k_transpose_v(const u16* __restrict__ V, u16* __restrict__ Vt) {
  int bh = blockIdx.z;
  int s0 = blockIdx.x * 32, d0 = blockIdx.y * 32;
  __shared__ u16 tile[32][33];
  int tx = threadIdx.x & 31, ty = threadIdx.x >> 5;
  const u16* Vb = V + (long)bh * 2048 * 64;
  u16* Vtb = Vt + (long)bh * 64 * 2048;
#pragma unroll
  for (int i = 0; i < 32; i += 8)
    tile[ty + i][tx] = Vb[(long)(s0 + ty + i) * 64 + d0 + tx];
  __syncthreads();
#pragma unroll
  for (int i = 0; i < 32; i += 8)
    Vtb[(long)(d0 + ty + i) * 2048 + s0 + tx] = tile[tx][ty + i];
}

// ---------------- NT GEMM core: C[128x128] = A[128xK] * Bt[128xK]^T ----------------

__device__ __forceinline__ void gemm_core(const u16* __restrict__ A, const u16* __restrict__ Bt,
                                          int K, long row0, long col0,
                                          u16* sA, u16* sB, f32x4 acc[4][4]) {
  const int t = threadIdx.x;
  const int lane = t & 63, g = lane >> 4, m16 = lane & 15;
  const int wid = t >> 6, wr = wid >> 1, wc = wid & 1;
  const int ldsbase = (t & ~63) << 4;
  const int nkt = K >> 6;
  for (int kt = 0; kt < nkt; ++kt) {
    const int k0 = kt << 6;
    __syncthreads();
#pragma unroll
    for (int it = 0; it < 4; ++it) {
      int i = it * 256 + t;
      int r = i >> 3, c = i & 7;
      int cs = c ^ (r & 7);
      async_lds16((char*)sA + it * 4096 + ldsbase, A + (row0 + r) * K + k0 + cs * 8);
    }
#pragma unroll
    for (int it = 0; it < 4; ++it) {
      int i = it * 256 + t;
      int r = i >> 3, c = i & 7;
      int cs = c ^ (r & 7);
      async_lds16((char*)sB + it * 4096 + ldsbase, Bt + (col0 + r) * K + k0 + cs * 8);
    }
    __syncthreads();
#pragma unroll
    for (int kk6 = 0; kk6 < 2; ++kk6) {
      const int ke = kk6 * 32 + 8 * g;
      bf16x8 av[4], bv[4];
#pragma unroll
      for (int mi = 0; mi < 4; ++mi) {
        int row = wr * 64 + mi * 16 + m16;
        av[mi] = *(const bf16x8*)((const char*)sA + (row << 7) + ((ke << 1) ^ ((row & 7) << 4)));
      }
#pragma unroll
      for (int ni = 0; ni < 4; ++ni) {
        int row = wc * 64 + ni * 16 + m16;
        bv[ni] = *(const bf16x8*)((const char*)sB + (row << 7) + ((ke << 1) ^ ((row & 7) << 4)));
      }
#pragma unroll
      for (int mi = 0; mi < 4; ++mi)
#pragma unroll
        for (int ni = 0; ni < 4; ++ni)
          acc[mi][ni] = MFMA16(av[mi], bv[ni], acc[mi][ni]);
    }
  }
}

// GEMM1: xb[4096][1024] x wqkvT[3072][1024]^T -> scatter Q,K,V [B,H,S,D] bf16
// XCD row-panel swizzle: xcd = L&7 owns row-tiles [xcd*4, xcd*4+4) (A-panel 1MB,
// L2-resident per XCD); idx&3 = row-in-panel, idx>>2 = col-tile. 1-D grid of 768.
__global__ __launch_bounds__(256) void k_gemm_qkv(const u16* __restrict__ xb, const u16* __restrict__ wT,
                                                  u16* __restrict__ Qo, u16* __restrict__ Ko,
                                                  u16* __restrict__ Vo) {
  __shared__ __align__(16) u16 sA[128 * 64];
  __shared__ __align__(16) u16 sB[128 * 64];
  f32x4 acc[4][4];
  const f32x4 z = {0.f, 0.f, 0.f, 0.f};
#pragma unroll
  for (int mi = 0; mi < 4; ++mi)
#pragma unroll
    for (int ni = 0; ni < 4; ++ni) acc[mi][ni] = z;
  const int L = blockIdx.x;
  const int xcd = L & 7, idx = L >> 3;          // idx 0..95
  const int rowt = xcd * 4 + (idx & 3);         // 0..31
  const int colt = idx >> 2;                    // 0..23
  long row0 = (long)rowt * 128, col0 = (long)colt * 128;
  gemm_core(xb, wT, 1024, row0, col0, sA, sB, acc);
  const int t = threadIdx.x;
  const int lane = t & 63, g = lane >> 4, m16 = lane & 15;
  const int wid = t >> 6, wr = wid >> 1, wc = wid & 1;
#pragma unroll
  for (int mi = 0; mi < 4; ++mi) {
#pragma unroll
    for (int ni = 0; ni < 4; ++ni) {
#pragma unroll
      for (int r = 0; r < 4; ++r) {
        int row = (int)row0 + wr * 64 + mi * 16 + 4 * g + r;
        int col = (int)col0 + wc * 64 + ni * 16 + m16;
        int h = col / 192, rem = col - h * 192;
        int which = rem >> 6, d = rem & 63;
        int b = row >> 11, s = row & 2047;
        long off = (((long)(b * 16 + h)) * 2048 + s) * 64 + d;
        float v = acc[mi][ni][r];
        if (which == 0) Qo[off] = f2bf(v * 0.18033688f);  // 0.125 * log2(e)
        else if (which == 1) Ko[off] = f2bf(v);
        else Vo[off] = f2bf(v);
      }
    }
  }
}

// GEMM2: Ob[4096][1024] x woutT[1024][1024]^T -> out f32 [4096][1024]
// Same XCD row-panel swizzle; 1-D grid of 256 (xcd owns 4 row-tiles x 8 col-tiles).
__global__ __launch_bounds__(256) void k_gemm_out(const u16* __restrict__ Ob, const u16* __restrict__ wT,
                                                  float* __restrict__ out) {
  __shared__ __align__(16) u16 sA[128 * 64];
  __shared__ __align__(16) u16 sB[128 * 64];
  f32x4 acc[4][4];
  const f32x4 z = {0.f, 0.f, 0.f, 0.f};
#pragma unroll
  for (int mi = 0; mi < 4; ++mi)
#pragma unroll
    for (int ni = 0; ni < 4; ++ni) acc[mi][ni] = z;
  const int L = blockIdx.x;
  const int xcd = L & 7, idx = L >> 3;          // idx 0..31
  const int rowt = xcd * 4 + (idx & 3);         // 0..31
  const int colt = idx >> 2;                    // 0..7
  long row0 = (long)rowt * 128, col0 = (long)colt * 128;
  gemm_core(Ob, wT, 1024, row0, col0, sA, sB, acc);
  const int t = threadIdx.x;
  const int lane = t & 63, g = lane >> 4, m16 = lane & 15;
  const int wid = t >> 6, wr = wid >> 1, wc = wid & 1;
#pragma unroll
  for (int mi = 0; mi < 4; ++mi) {
#pragma unroll
    for (int ni = 0; ni < 4; ++ni) {
#pragma unroll
      for (int r = 0; r < 4; ++r) {
        long row = row0 + wr * 64 + mi * 16 + 4 * g + r;
        long col = col0 + wc * 64 + ni * 16 + m16;
        out[row * 1024 + col] = acc[mi][ni][r];
      }
    }
  }
}

// ---------------- causal flash attention: LDS-shared K/V + lean in-register body ----------------
// Block = 256 thr = 4 waves, QBLK=128 (wave w -> strip qt*4+w), KVBLK=64, K/V
// double-buffered in LDS (32KB) via global_load_lds shared by all 4 waves -> 4x less
// global K/V traffic. Per-wave math: swapped QK 32x32 (lane owns q-col), fixed-max
// exp2 softmax, permlane P->PV. One barrier per tile; wave-dead sub-blocks skipped.

template <bool DIAG>
__device__ __forceinline__ void attn_sub(const char* Kt, const char* Vt, int bsub,
                                         bf16x8 qf0, bf16x8 qf1, bf16x8 qf2, bf16x8 qf3,
                                         f32x16& acc0, f32x16& acc1, float& l,
                                         int q5, int hi) {
  const int x7 = q5 & 7;
  const int rowK = (bsub * 32 + q5) << 7;
  bf16x8 k0 = *(const bf16x8*)(Kt + rowK + (((0 + hi) ^ x7) << 4));
  bf16x8 k1 = *(const bf16x8*)(Kt + rowK + (((2 + hi) ^ x7) << 4));
  bf16x8 k2 = *(const bf16x8*)(Kt + rowK + (((4 + hi) ^ x7) << 4));
  bf16x8 k3 = *(const bf16x8*)(Kt + rowK + (((6 + hi) ^ x7) << 4));
  const int rowV0 = q5 << 7, rowV1 = (q5 + 32) << 7;
  bf16x8 v00 = *(const bf16x8*)(Vt + rowV0 + (((bsub * 4 + 0 + hi) ^ x7) << 4));
  bf16x8 v01 = *(const bf16x8*)(Vt + rowV1 + (((bsub * 4 + 0 + hi) ^ x7) << 4));
  bf16x8 v10 = *(const bf16x8*)(Vt + rowV0 + (((bsub * 4 + 2 + hi) ^ x7) << 4));
  bf16x8 v11 = *(const bf16x8*)(Vt + rowV1 + (((bsub * 4 + 2 + hi) ^ x7) << 4));

  f32x16 s;
#pragma unroll
  for (int r = 0; r < 16; ++r) s[r] = 0.f;
  s = MFMA32(k0, qf0, s);
  s = MFMA32(k1, qf1, s);
  s = MFMA32(k2, qf2, s);
  s = MFMA32(k3, qf3, s);

  float p[16];
#pragma unroll
  for (int r = 0; r < 16; ++r) {
    float pv = exp2_fast(s[r]);
    if (DIAG) {
      int crow = (r & 3) + 8 * (r >> 2) + 4 * hi;
      pv = (crow <= q5) ? pv : 0.f;
    }
    p[r] = pv;
  }
  l += (((p[0] + p[1]) + (p[2] + p[3])) + ((p[4] + p[5]) + (p[6] + p[7]))) +
       (((p[8] + p[9]) + (p[10] + p[11])) + ((p[12] + p[13]) + (p[14] + p[15])));

  u32 a0 = cvt_pk_bf16(p[0], p[1]), a1 = cvt_pk_bf16(p[2], p[3]);
  u32 b0 = cvt_pk_bf16(p[4], p[5]), b1 = cvt_pk_bf16(p[6], p[7]);
  pswap(a0, b0); pswap(a1, b1);
  u32 c0 = cvt_pk_bf16(p[8], p[9]), c1 = cvt_pk_bf16(p[10], p[11]);
  u32 d0 = cvt_pk_bf16(p[12], p[13]), d1 = cvt_pk_bf16(p[14], p[15]);
  pswap(c0, d0); pswap(c1, d1);
  u32x4 t0; t0[0] = a0; t0[1] = a1; t0[2] = b0; t0[3] = b1;
  u32x4 t1; t1[0] = c0; t1[1] = c1; t1[2] = d0; t1[3] = d1;
  bf16x8 pa0 = __builtin_bit_cast(bf16x8, t0);  // keys +0..15, k-slot order
  bf16x8 pa1 = __builtin_bit_cast(bf16x8, t1);  // keys +16..31

  acc0 = MFMA32(pa0, v00, acc0);
  acc1 = MFMA32(pa0, v01, acc1);
  acc0 = MFMA32(pa1, v10, acc0);
  acc1 = MFMA32(pa1, v11, acc1);
}

// Q,K: [32 bh][2048][64] bf16 (Q pre-scaled by 0.125*log2e); Vt: [32 bh][64][2048] bf16
__global__ __launch_bounds__(256) void k_attn(const u16* __restrict__ Qg, const u16* __restrict__ Kg,
                                              const u16* __restrict__ Vtg, u16* __restrict__ Og) {
  __shared__ __align__(16) u16 sK[2][64 * 64];  // [key][d] swizzled, 8KB per buffer
  __shared__ __align__(16) u16 sV[2][64 * 64];  // [d][key] swizzled
  const int t = threadIdx.x;
  const int lane = t & 63, q5 = lane & 31, hi = lane >> 5, w = t >> 6;
  const int L = blockIdx.x;
  const int bh = L & 31, q16 = L >> 5;                 // XCD affinity: L%8 == bh%8
  const int qt = (q16 < 8) ? q16 : (23 - q16);         // (qt, 15-qt) complementary ordering
  const int b = bh >> 4, h = bh & 15;
  const u16* Qh = Qg + (long)bh * 131072;
  const u16* Kh = Kg + (long)bh * 131072;
  const u16* Vh = Vtg + (long)bh * 131072;
  char* sKb = (char*)sK;
  char* sVb = (char*)sV;

  const int strip = qt * 4 + w;
  const int q0w = strip * 32;
  const int nkt = 2 * qt + 2;  // tiles staged by this block

  // Q fragments for this wave's strip
  const u16* Qp = Qh + (long)(q0w + q5) * 64 + hi * 8;
  bf16x8 qf0 = *(const bf16x8*)(Qp);
  bf16x8 qf1 = *(const bf16x8*)(Qp + 16);
  bf16x8 qf2 = *(const bf16x8*)(Qp + 32);
  bf16x8 qf3 = *(const bf16x8*)(Qp + 48);

  f32x16 acc0, acc1;
#pragma unroll
  for (int r = 0; r < 16; ++r) { acc0[r] = 0.f; acc1[r] = 0.f; }
  float l = 0.f;

  auto stage = [&](int buf, int kt) {
    const int kbase = kt << 6;
#pragma unroll
    for (int ps = 0; ps < 2; ++ps) {
      int i = ps * 256 + t;
      int r = i >> 3, c = i & 7, cs = c ^ (r & 7);
      async_lds16(sKb + buf * 8192 + i * 16, Kh + (long)(kbase + r) * 64 + cs * 8);
    }
#pragma unroll
    for (int ps = 0; ps < 2; ++ps) {
      int i = ps * 256 + t;
      int d = i >> 3, c = i & 7, cs = c ^ (d & 7);
      async_lds16(sVb + buf * 8192 + i * 16, Vh + (long)d * 2048 + kbase + cs * 8);
    }
  };

  stage(0, 0);
  int cur = 0;
  for (int kt = 0; kt < nkt; ++kt) {
    __syncthreads();  // tile kt staged (vmcnt drain) + everyone done reading buf cur^1
    if (kt + 1 < nkt) stage(cur ^ 1, kt + 1);
    const char* Kt = sKb + cur * 8192;
    const char* Vt = sVb + cur * 8192;
    const int c2 = 2 * kt;
    if (c2 <= strip) {
      if (c2 == strip) attn_sub<true>(Kt, Vt, 0, qf0, qf1, qf2, qf3, acc0, acc1, l, q5, hi);
      else             attn_sub<false>(Kt, Vt, 0, qf0, qf1, qf2, qf3, acc0, acc1, l, q5, hi);
    }
    if (c2 + 1 <= strip) {
      if (c2 + 1 == strip) attn_sub<true>(Kt, Vt, 1, qf0, qf1, qf2, qf3, acc0, acc1, l, q5, hi);
      else                 attn_sub<false>(Kt, Vt, 1, qf0, qf1, qf2, qf3, acc0, acc1, l, q5, hi);
    }
    cur ^= 1;
  }

  // epilogue (no LDS use -> no final barrier)
  l += __shfl_xor(l, 32);
  float linv = 1.0f / l;
  const long orow_base = (long)b * 2048;
#pragma unroll
  for (int r = 0; r < 16; ++r) {
    int crow = (r & 3) + 8 * (r >> 2) + 4 * hi;
    float lf = __shfl(linv, crow);
    long orow = orow_base + q0w + crow;
    Og[orow * 1024 + h * 64 + q5] = f2bf(acc0[r] * lf);
    Og[orow * 1024 + h * 64 + 32 + q5] = f2bf(acc1[r] * lf);
  }
}

// ---------------- launch ----------------

extern "C" void kernel_launch(void* const* d_in, const int* in_sizes, int n_in,
                              void* d_out, int out_size, void* d_ws, size_t ws_size,
                              hipStream_t stream) {
  const float* x = (const float*)d_in[0];
  const float* w_qkv = (const float*)d_in[1];
  const float* w_out = (const float*)d_in[2];
  float* out = (float*)d_out;
  char* ws = (char*)d_ws;

  u16* xb    = (u16*)(ws + 0);          // 8 MB, reused as Ob after attention
  u16* wqkvT = (u16*)(ws + 8388608L);   // 6 MB
  u16* woutT = (u16*)(ws + 14680064L);  // 2 MB
  u16* Qb    = (u16*)(ws + 16777216L);  // 8 MB
  u16* Kb    = (u16*)(ws + 25165824L);  // 8 MB
  u16* Vb    = (u16*)(ws + 33554432L);  // 8 MB
  u16* Vt    = (u16*)(ws + 41943040L);  // 8 MB  (total 48 MB)
  u16* Ob    = xb;                      // alias: xb dead after GEMM1

  k_cvt<<<4096, 256, 0, stream>>>(x, xb, 4194304);
  k_transpose_cvt<<<dim3(96, 32), 256, 0, stream>>>(w_qkv, wqkvT, 1024, 3072);
  k_transpose_cvt<<<dim3(32, 32), 256, 0, stream>>>(w_out, woutT, 1024, 1024);
  k_gemm_qkv<<<dim3(768), 256, 0, stream>>>(xb, wqkvT, Qb, Kb, Vb);
  k_transpose_v<<<dim3(64, 2, 32), 256, 0, stream>>>(Vb, Vt);
  k_attn<<<dim3(512), 256, 0, stream>>>(Qb, Kb, Vt, Ob);
  k_gemm_out<<<dim3(256), 256, 0, stream>>>(Ob, woutT, out);
}